// Round 7
// baseline (391.744 us; speedup 1.0000x reference)
//
#include <hip/hip_runtime.h>

#define BB 8192
#define LL 40
#define VV 100000
#define NEG_INF_F (-4294967295.0f)
#define XS 136    // sX row stride (bf16): 128 + 8 pad
#define HS 104    // sH1 row stride (bf16), K padded 80->96
#define XGS 480   // global info_all row stride (bf16), K padded 456->480

typedef __attribute__((ext_vector_type(8))) short short8;
typedef __attribute__((ext_vector_type(4))) float f32x4;

__device__ __forceinline__ unsigned short f2bf(float f) {
  unsigned u = __float_as_uint(f);
  u += 0x7FFFu + ((u >> 16) & 1u);
  return (unsigned short)(u >> 16);
}
__device__ __forceinline__ float bf2f(unsigned short s) {
  return __uint_as_float(((unsigned)s) << 16);
}

// B' = bf16( Wsd + q * Wd ), elementwise over a lane's 8-element fragment
__device__ __forceinline__ short8 fuseB(short8 wsd, short8 wd, float4 qa, float4 qb) {
  float qv[8] = {qa.x, qa.y, qa.z, qa.w, qb.x, qb.y, qb.z, qb.w};
  short8 o;
#pragma unroll
  for (int j = 0; j < 8; j++)
    o[j] = (short)f2bf(bf2f((unsigned short)wsd[j]) + qv[j] * bf2f((unsigned short)wd[j]));
  return o;
}

// ---------------- prep (fused, parallel) ----------------
__global__ void prep_all(const float* __restrict__ W1, float* __restrict__ wqcT,
                         unsigned short* __restrict__ WsdpT,
                         const float* __restrict__ aW2, unsigned short* __restrict__ W2bT,
                         const float* __restrict__ fW2, unsigned short* __restrict__ W2fT,
                         const float* __restrict__ fW1, const float* __restrict__ g,
                         const float* __restrict__ vr, unsigned short* __restrict__ W1fT,
                         const float* __restrict__ fb1, const float* __restrict__ be,
                         const float* __restrict__ mn, float* __restrict__ b1p) {
  __shared__ float red[4];
  int bid = blockIdx.x, t = threadIdx.x;
  if (bid < 40) {
    int i = bid * 256 + t;           // exactly 10240
    int h = i >> 7, k = i & 127;
    float a = W1[k * 80 + h];
    float b = W1[(128 + k) * 80 + h];
    float c = W1[(256 + k) * 80 + h];
    float d = W1[(384 + k) * 80 + h];
    wqcT[h * 132 + k] = a + c;
    WsdpT[h * 256 + k] = f2bf(b - c);
    WsdpT[h * 256 + 128 + k] = f2bf(d);
  } else if (bid < 58) {
    int i = (bid - 40) * 256 + t;    // exactly 4608
    int n = i / 96, k = i % 96;
    W2bT[i] = (n < 40 && k < 80) ? f2bf(aW2[k * 40 + n]) : (unsigned short)0;
  } else if (bid < 76) {
    int i = (bid - 58) * 256 + t;
    int n = i / 96, k = i % 96;
    W2fT[i] = (n < 40 && k < 80) ? f2bf(fW2[k * 40 + n]) : (unsigned short)0;
  } else if (bid < 226) {
    int i = (bid - 76) * 256 + t;    // exactly 38400
    int n = i / 480, k = i % 480;
    float v = 0.f;
    if (k < 456) v = fW1[k * 80 + n] * g[k] * rsqrtf(vr[k] + 1e-3f);
    W1fT[i] = f2bf(v);
  } else {
    int n = bid - 226;               // 0..79
    float p = 0.f;
    for (int k = t; k < 456; k += 256) {
      float sc = g[k] * rsqrtf(vr[k] + 1e-3f);
      p += (be[k] - mn[k] * sc) * fW1[k * 80 + n];
    }
    for (int off = 32; off; off >>= 1) p += __shfl_xor(p, off, 64);
    if ((t & 63) == 0) red[t >> 6] = p;
    __syncthreads();
    if (t == 0) b1p[n] = fb1[n] + red[0] + red[1] + red[2] + red[3];
  }
}

// ---------------- kernel A: attention + pool, one row per block ----------------
// Manual LDS pool, 21632 B -> up to 6-7 blocks/CU.
// Layout (bytes):
//   [0     .. 10880)  sX  : 40 x 136 bf16 (s only; OOB A-reads land in-pool, discarded rows)
//   [10880 .. 19200)  sH1 : 40 x 104 bf16 (cols 80..95 MUST be zeroed: layer2 K-pad;
//                           B-side is zero there but LDS garbage can be NaN and NaN*0=NaN)
//   [19200 .. 21632)  floats: sQ[128] sQCp[160] sOther[200] sAtt[40] sLogit[40] sMask[40]

__launch_bounds__(256, 6)
__global__ void din_att(const float* __restrict__ dense, const int* __restrict__ sparsei,
                        const int* __restrict__ seqi, const int* __restrict__ itemi,
                        const float* __restrict__ embS, const float* __restrict__ embQ,
                        const float* __restrict__ wqcT, const unsigned short* __restrict__ WsdpT,
                        const unsigned short* __restrict__ W2bT,
                        const float* __restrict__ ab1, const float* __restrict__ ab2,
                        const float* __restrict__ aWf, const float* __restrict__ abf,
                        unsigned short* __restrict__ Xg) {
  __shared__ __align__(16) char smem[21632];
  unsigned short* sX  = (unsigned short*)smem;             // 40 x 136
  unsigned short* sH1 = (unsigned short*)(smem + 10880);   // 40 x 104
  float* sQ     = (float*)(smem + 19200);                  // 128
  float* sQCp   = sQ + 128;                                // 160 (split-K qconst)
  float* sOther = sQCp + 160;                              // 200
  float* sAtt   = sOther + 200;                            // 40
  float* sLogit = sAtt + 40;                               // 40
  float* sMask  = sLogit + 40;                             // 40

  const int t = threadIdx.x;        // 0..255
  const int b = blockIdx.x;
  const int wv = t >> 6, ln = t & 63, m16 = ln & 15, quad = ln >> 4;

  // ---- pre-barrier prefetch: own-nt Wsd/Wd fragments (K=128) ----
  short8 wsdF[4], wdF[4];
  {
    const unsigned short* br = WsdpT + (size_t)(wv * 16 + m16) * 256 + quad * 8;
#pragma unroll
    for (int kt = 0; kt < 4; kt++) {
      wsdF[kt] = *(const short8*)(br + kt * 32);
      wdF[kt]  = *(const short8*)(br + 128 + kt * 32);
    }
  }

  // ---- phase 1: gathers + zero inits + mask cache ----
  if (t < 32) {
    int f = t >> 4, sub = t & 15;
    int idx = itemi[b * 2 + f];
    float4 v = *(const float4*)(embQ + ((size_t)(f * VV + idx)) * 64 + sub * 4);
    *(float4*)(sQ + f * 64 + sub * 4) = v;
  } else if (t < 80) {
    int j = t - 32, f = j >> 4, sub = j & 15;
    int idx = sparsei[b * 3 + f];
    float4 v = *(const float4*)(embS + ((size_t)(f * VV + idx)) * 64 + sub * 4);
    *(float4*)(sOther + 8 + f * 64 + sub * 4) = v;
  } else if (t < 88) {
    sOther[t - 80] = dense[b * 8 + (t - 80)];
  } else if (t < 128) {
    sLogit[t - 88] = 0.f;
  }
  for (int i = t; i < 1280; i += 256) {
    int r = i >> 4, sub = i & 15;
    int l = r >> 1, f = r & 1;
    int idx = seqi[b * 80 + r];
    float4 v = *(const float4*)(embQ + ((size_t)(f * VV + idx)) * 64 + sub * 4);
    ushort4 u;
    u.x = f2bf(v.x); u.y = f2bf(v.y); u.z = f2bf(v.z); u.w = f2bf(v.w);
    *(ushort4*)(sX + l * XS + f * 64 + sub * 4) = u;
    if (((r & 1) | sub) == 0) sMask[l] = (idx != 0) ? 0.f : NEG_INF_F;
  }
  for (int i = t; i < 320; i += 256) {   // sH1 K-pad cols 80..95, rows 0..39 (NaN guard)
    int r = i >> 3, c = i & 7;
    ((unsigned*)sH1)[r * 52 + 40 + c] = 0u;
  }
  __syncthreads();

  // ---- phase 2: split-K qconst (t<160) + per-lane B' fragment build (all) ----
  if (t < 160) {
    int h = (t < 80) ? t : t - 80;
    int k0 = (t < 80) ? 0 : 64;
    float acc = (t < 80) ? ab1[h] : 0.f;
    const float* wq = wqcT + h * 132 + k0;
    const float* qq = sQ + k0;
    for (int k = 0; k < 64; k += 4) {
      float4 w = *(const float4*)(wq + k);
      float4 q = *(const float4*)(qq + k);
      acc += q.x * w.x + q.y * w.y + q.z * w.z + q.w * w.w;
    }
    sQCp[t] = acc;
  }
  short8 Bp[4], Bp4[4];
  {
#pragma unroll
    for (int kt = 0; kt < 4; kt++) {
      int k0 = quad * 8 + kt * 32;
      float4 qa = *(const float4*)(sQ + k0);
      float4 qb = *(const float4*)(sQ + k0 + 4);
      Bp[kt] = fuseB(wsdF[kt], wdF[kt], qa, qb);
    }
    if (wv < 3) {   // nt = 4 fragments (loaded now; L2-hot)
      const unsigned short* br = WsdpT + (size_t)(64 + m16) * 256 + quad * 8;
#pragma unroll
      for (int kt = 0; kt < 4; kt++) {
        short8 w1 = *(const short8*)(br + kt * 32);
        short8 w2 = *(const short8*)(br + 128 + kt * 32);
        int k0 = quad * 8 + kt * 32;
        Bp4[kt] = fuseB(w1, w2, *(const float4*)(sQ + k0), *(const float4*)(sQ + k0 + 4));
      }
    }
  }
  __syncthreads();

  // ---- phase 3: layer1 MFMA, K=128, wave = N-tile; waves 0-2 also cover nt=4 ----
  {
    const int h = wv * 16 + m16;
    const float qc = sQCp[h] + sQCp[80 + h];
#pragma unroll
    for (int mt = 0; mt < 3; mt++) {
      f32x4 acc = {0.f, 0.f, 0.f, 0.f};
      const unsigned short* ar = sX + (mt * 16 + m16) * XS + quad * 8;
#pragma unroll
      for (int kt = 0; kt < 4; kt++) {
        short8 a = *(const short8*)(ar + kt * 32);
        acc = __builtin_amdgcn_mfma_f32_16x16x32_bf16(a, Bp[kt], acc, 0, 0, 0);
      }
#pragma unroll
      for (int r = 0; r < 4; r++) {
        int l = mt * 16 + quad * 4 + r;
        if (l < 40) {
          float z = acc[r] + qc;
          sH1[l * HS + h] = f2bf(1.f / (1.f + __expf(-z)));
        }
      }
    }
    if (wv < 3) {   // nt = 4, mt = wv
      f32x4 acc = {0.f, 0.f, 0.f, 0.f};
      const unsigned short* ar = sX + (wv * 16 + m16) * XS + quad * 8;
#pragma unroll
      for (int kt = 0; kt < 4; kt++) {
        short8 a = *(const short8*)(ar + kt * 32);
        acc = __builtin_amdgcn_mfma_f32_16x16x32_bf16(a, Bp4[kt], acc, 0, 0, 0);
      }
      int h4 = 64 + m16;
      float qc4 = sQCp[h4] + sQCp[80 + h4];
#pragma unroll
      for (int r = 0; r < 4; r++) {
        int l = wv * 16 + quad * 4 + r;
        if (l < 40) {
          float z = acc[r] + qc4;
          sH1[l * HS + h4] = f2bf(1.f / (1.f + __expf(-z)));
        }
      }
    }
  }
  __syncthreads();

  // ---- phase 4: layer2 MFMA + fused logit reduction into sLogit ----
  for (int tile = wv; tile < 9; tile += 4) {
    int mt = tile / 3, nt = tile % 3;
    f32x4 acc = {0.f, 0.f, 0.f, 0.f};
    const unsigned short* ar = sH1 + (mt * 16 + m16) * HS + quad * 8;
    const unsigned short* br = W2bT + (nt * 16 + m16) * 96 + quad * 8;
#pragma unroll
    for (int kt = 0; kt < 3; kt++) {
      short8 a = *(const short8*)(ar + kt * 32);
      short8 bb = *(const short8*)(br + kt * 32);
      acc = __builtin_amdgcn_mfma_f32_16x16x32_bf16(a, bb, acc, 0, 0, 0);
    }
    int j = nt * 16 + m16;
    float b2 = (j < 40) ? ab2[j] : 0.f;
    float wf = (j < 40) ? aWf[j] : 0.f;
    float c[4];
#pragma unroll
    for (int r = 0; r < 4; r++) {
      float h2 = 1.f / (1.f + __expf(-(acc[r] + b2)));
      c[r] = (j < 40) ? h2 * wf : 0.f;    // gate garbage j-lanes (NaN-safe select)
    }
#pragma unroll
    for (int off = 1; off < 16; off <<= 1) {
#pragma unroll
      for (int r = 0; r < 4; r++) c[r] += __shfl_xor(c[r], off, 64);
    }
    if (m16 == 0) {
#pragma unroll
      for (int r = 0; r < 4; r++) {
        int l = mt * 16 + quad * 4 + r;
        if (l < 40) atomicAdd(&sLogit[l], c[r]);
      }
    }
  }
  __syncthreads();

  // ---- phase 5: softmax (wave 0) || store item/other/pad cols of Xg (waves 1-3) ----
  if (wv == 0) {
    float logit = -3.0e38f;
    if (t < 40) logit = sLogit[t] + abf[0] + sMask[t];
    float mx = logit;
    for (int off = 32; off; off >>= 1) mx = fmaxf(mx, __shfl_xor(mx, off, 64));
    float ex = (t < 40) ? __expf(logit - mx) : 0.f;
    float sm = ex;
    for (int off = 32; off; off >>= 1) sm += __shfl_xor(sm, off, 64);
    if (t < 40) sAtt[t] = ex / sm;
  } else {
    int j = t - 64;                                  // 0..191
    unsigned* xr = (unsigned*)(Xg + (size_t)b * XGS);
    if (j < 64) {
      xr[64 + j] = (unsigned)f2bf(sQ[2 * j]) | ((unsigned)f2bf(sQ[2 * j + 1]) << 16);
    } else if (j < 164) {
      int p = j - 64;
      xr[128 + p] = (unsigned)f2bf(sOther[2 * p]) | ((unsigned)f2bf(sOther[2 * p + 1]) << 16);
    } else if (j < 176) {
      xr[228 + (j - 164)] = 0u;                      // K-pad cols 456..479
    }
  }
  __syncthreads();

  // ---- phase 6: attention pool -> Xg cols 0..127 ----
  if (t < 128) {
    float acc = 0.f;
    for (int l = 0; l < 40; l++) acc += sAtt[l] * bf2f(sX[l * XS + t]);
    Xg[(size_t)b * XGS + t] = f2bf(acc);
  }
}

// ---------------- kernel B: batched FFN GEMM, 16 rows per block ----------------

__launch_bounds__(256, 2)
__global__ void din_ffn(const unsigned short* __restrict__ Xg,
                        const unsigned short* __restrict__ W1fT, const float* __restrict__ b1p,
                        const float* __restrict__ fa1,
                        const unsigned short* __restrict__ W2fT, const float* __restrict__ fb2,
                        const float* __restrict__ fa2,
                        const float* __restrict__ oW, const float* __restrict__ ob,
                        float* __restrict__ out) {
  __shared__ __align__(16) unsigned short sXB[16 * 488];
  __shared__ __align__(16) unsigned short sH1B[16 * HS];
  __shared__ float sH2B[16 * 41];
  const int t = threadIdx.x, blk = blockIdx.x;
  const int wv = t >> 6, ln = t & 63, m16 = ln & 15, quad = ln >> 4;

  // prefetch GEMM1 B-fragments for nt = wv (15 frags, K=480)
  short8 Bf[15];
  {
    const unsigned short* br = W1fT + (size_t)(wv * 16 + m16) * 480 + quad * 8;
#pragma unroll
    for (int kt = 0; kt < 15; kt++) Bf[kt] = *(const short8*)(br + kt * 32);
  }

  // stage X tile (16 rows x 480 bf16) + zero H1 K-pad
  for (int i = t; i < 960; i += 256) {
    int r = i / 60, c = i % 60;
    *(uint4*)(sXB + r * 488 + c * 8) =
        *(const uint4*)(Xg + (size_t)(blk * 16 + r) * XGS + c * 8);
  }
  if (t < 128) {
    int r = t >> 3, c = t & 7;
    ((unsigned*)sH1B)[r * 52 + 40 + c] = 0u;
  }
  __syncthreads();

  // GEMM1: [16x480] @ [480x80]; wave = N-tile; wave 0 also does nt=4
  {
    int h = wv * 16 + m16;
    f32x4 acc = {0.f, 0.f, 0.f, 0.f};
    const unsigned short* ar = sXB + m16 * 488 + quad * 8;
#pragma unroll
    for (int kt = 0; kt < 15; kt++) {
      short8 a = *(const short8*)(ar + kt * 32);
      acc = __builtin_amdgcn_mfma_f32_16x16x32_bf16(a, Bf[kt], acc, 0, 0, 0);
    }
    float b1v = b1p[h], a1v = fa1[h];
#pragma unroll
    for (int r = 0; r < 4; r++) {
      int l = quad * 4 + r;
      float z = acc[r] + b1v;
      z = z > 0.f ? z : a1v * z;
      sH1B[l * HS + h] = f2bf(z);
    }
    if (wv == 0) {   // nt = 4
      short8 B4[15];
      const unsigned short* br = W1fT + (size_t)(64 + m16) * 480 + quad * 8;
#pragma unroll
      for (int kt = 0; kt < 15; kt++) B4[kt] = *(const short8*)(br + kt * 32);
      f32x4 acc4 = {0.f, 0.f, 0.f, 0.f};
#pragma unroll
      for (int kt = 0; kt < 15; kt++) {
        short8 a = *(const short8*)(ar + kt * 32);
        acc4 = __builtin_amdgcn_mfma_f32_16x16x32_bf16(a, B4[kt], acc4, 0, 0, 0);
      }
      int h4 = 64 + m16;
      float b1v4 = b1p[h4], a1v4 = fa1[h4];
#pragma unroll
      for (int r = 0; r < 4; r++) {
        int l = quad * 4 + r;
        float z = acc4[r] + b1v4;
        z = z > 0.f ? z : a1v4 * z;
        sH1B[l * HS + h4] = f2bf(z);
      }
    }
  }
  __syncthreads();

  // GEMM2: [16x96] @ [96x48], waves 0-2
  if (wv < 3) {
    f32x4 acc = {0.f, 0.f, 0.f, 0.f};
    const unsigned short* ar = sH1B + m16 * HS + quad * 8;
    const unsigned short* br = W2fT + (wv * 16 + m16) * 96 + quad * 8;
#pragma unroll
    for (int kt = 0; kt < 3; kt++) {
      short8 a = *(const short8*)(ar + kt * 32);
      short8 bb = *(const short8*)(br + kt * 32);
      acc = __builtin_amdgcn_mfma_f32_16x16x32_bf16(a, bb, acc, 0, 0, 0);
    }
    int j = wv * 16 + m16;
    if (j < 40) {
      float b2 = fb2[j], a2 = fa2[j];
#pragma unroll
      for (int r = 0; r < 4; r++) {
        int l = quad * 4 + r;
        float z = acc[r] + b2;
        sH2B[l * 41 + j] = z > 0.f ? z : a2 * z;
      }
    }
  }
  __syncthreads();

  // final dot(40) + sigmoid
  if (t < 16) {
    float acc = ob[0];
    for (int j = 0; j < 40; j++) acc += sH2B[t * 41 + j] * oW[j];
    out[blk * 16 + t] = 1.f / (1.f + __expf(-acc));
  }
}

// ---------------- launch ----------------

extern "C" void kernel_launch(void* const* d_in, const int* in_sizes, int n_in,
                              void* d_out, int out_size, void* d_ws, size_t ws_size,
                              hipStream_t stream) {
  const float* dense  = (const float*)d_in[0];
  const int*   sparsei = (const int*)d_in[1];
  const int*   seqi   = (const int*)d_in[2];
  const int*   itemi  = (const int*)d_in[3];
  const float* embS   = (const float*)d_in[4];
  const float* embQ   = (const float*)d_in[5];
  const float* aW1    = (const float*)d_in[6];
  const float* ab1    = (const float*)d_in[7];
  const float* aW2    = (const float*)d_in[8];
  const float* ab2    = (const float*)d_in[9];
  const float* aWf    = (const float*)d_in[10];
  const float* abf    = (const float*)d_in[11];
  const float* bng    = (const float*)d_in[12];
  const float* bnb    = (const float*)d_in[13];
  const float* bnm    = (const float*)d_in[14];
  const float* bnv    = (const float*)d_in[15];
  const float* fW1    = (const float*)d_in[16];
  const float* fb1    = (const float*)d_in[17];
  const float* fa1    = (const float*)d_in[18];
  const float* fW2    = (const float*)d_in[19];
  const float* fb2    = (const float*)d_in[20];
  const float* fa2    = (const float*)d_in[21];
  const float* oW     = (const float*)d_in[22];
  const float* ob     = (const float*)d_in[23];
  float* out = (float*)d_out;

  float* ws = (float*)d_ws;
  float* wqcT = ws;                                          // 10560 f
  float* b1p  = ws + 10560;                                  // 80 f
  unsigned short* WsdpT = (unsigned short*)(ws + 10640);     // 20480 u16 = 10240 f
  unsigned short* W2bT  = (unsigned short*)(ws + 20880);     // 4608 u16 = 2304 f
  unsigned short* W2fT  = (unsigned short*)(ws + 23184);     // 4608 u16 = 2304 f
  unsigned short* W1fT  = (unsigned short*)(ws + 25488);     // 38400 u16 = 19200 f
  unsigned short* Xg    = (unsigned short*)(ws + 44688);     // 8192*480 u16

  prep_all<<<306, 256, 0, stream>>>(aW1, wqcT, WsdpT, aW2, W2bT, fW2, W2fT,
                                    fW1, bng, bnv, W1fT, fb1, bnb, bnm, b1p);
  din_att<<<BB, 256, 0, stream>>>(dense, sparsei, seqi, itemi, embS, embQ,
                                  wqcT, WsdpT, W2bT, ab1, ab2, aWf, abf, Xg);
  din_ffn<<<512, 256, 0, stream>>>(Xg, W1fT, b1p, fa1, W2fT, fb2, fa2, oW, ob, out);
}

// Round 8
// 314.331 us; speedup vs baseline: 1.2463x; 1.2463x over previous
//
#include <hip/hip_runtime.h>

#define BB 8192
#define LL 40
#define VV 100000
#define NEG_INF_F (-4294967295.0f)
#define XS 136    // sX row stride (bf16): 128 + 8 pad
#define HS 104    // sH1 row stride (bf16), K padded 80->96
#define XGS 480   // global info_all row stride (bf16), K padded 456->480

typedef __attribute__((ext_vector_type(8))) short short8;
typedef __attribute__((ext_vector_type(4))) float f32x4;

__device__ __forceinline__ unsigned short f2bf(float f) {
  unsigned u = __float_as_uint(f);
  u += 0x7FFFu + ((u >> 16) & 1u);
  return (unsigned short)(u >> 16);
}
__device__ __forceinline__ float bf2f(unsigned short s) {
  return __uint_as_float(((unsigned)s) << 16);
}

// B' = bf16( Wsd + q * Wd ), elementwise over a lane's 8-element fragment
__device__ __forceinline__ short8 fuseB(short8 wsd, short8 wd, float4 qa, float4 qb) {
  float qv[8] = {qa.x, qa.y, qa.z, qa.w, qb.x, qb.y, qb.z, qb.w};
  short8 o;
#pragma unroll
  for (int j = 0; j < 8; j++)
    o[j] = (short)f2bf(bf2f((unsigned short)wsd[j]) + qv[j] * bf2f((unsigned short)wd[j]));
  return o;
}

// ---------------- prep (fused, parallel) ----------------
__global__ void prep_all(const float* __restrict__ W1, float* __restrict__ wqcT,
                         unsigned short* __restrict__ WsdpT,
                         const float* __restrict__ aW2, unsigned short* __restrict__ W2bT,
                         const float* __restrict__ fW2, unsigned short* __restrict__ W2fT,
                         const float* __restrict__ fW1, const float* __restrict__ g,
                         const float* __restrict__ vr, unsigned short* __restrict__ W1fT,
                         const float* __restrict__ fb1, const float* __restrict__ be,
                         const float* __restrict__ mn, float* __restrict__ b1p) {
  __shared__ float red[4];
  int bid = blockIdx.x, t = threadIdx.x;
  if (bid < 40) {
    int i = bid * 256 + t;           // exactly 10240
    int h = i >> 7, k = i & 127;
    float a = W1[k * 80 + h];
    float b = W1[(128 + k) * 80 + h];
    float c = W1[(256 + k) * 80 + h];
    float d = W1[(384 + k) * 80 + h];
    wqcT[h * 132 + k] = a + c;
    WsdpT[h * 256 + k] = f2bf(b - c);
    WsdpT[h * 256 + 128 + k] = f2bf(d);
  } else if (bid < 58) {
    int i = (bid - 40) * 256 + t;    // exactly 4608
    int n = i / 96, k = i % 96;
    W2bT[i] = (n < 40 && k < 80) ? f2bf(aW2[k * 40 + n]) : (unsigned short)0;
  } else if (bid < 76) {
    int i = (bid - 58) * 256 + t;
    int n = i / 96, k = i % 96;
    W2fT[i] = (n < 40 && k < 80) ? f2bf(fW2[k * 40 + n]) : (unsigned short)0;
  } else if (bid < 226) {
    int i = (bid - 76) * 256 + t;    // exactly 38400
    int n = i / 480, k = i % 480;
    float v = 0.f;
    if (k < 456) v = fW1[k * 80 + n] * g[k] * rsqrtf(vr[k] + 1e-3f);
    W1fT[i] = f2bf(v);
  } else {
    int n = bid - 226;               // 0..79
    float p = 0.f;
    for (int k = t; k < 456; k += 256) {
      float sc = g[k] * rsqrtf(vr[k] + 1e-3f);
      p += (be[k] - mn[k] * sc) * fW1[k * 80 + n];
    }
    for (int off = 32; off; off >>= 1) p += __shfl_xor(p, off, 64);
    if ((t & 63) == 0) red[t >> 6] = p;
    __syncthreads();
    if (t == 0) b1p[n] = fb1[n] + red[0] + red[1] + red[2] + red[3];
  }
}

// ---------------- kernel A: attention + pool, one row per block ----------------
// LDS pool 21632 B. Register budget is the binding constraint:
// NO weight fragments may be live across phase 1 (caused 360 MB scratch spill in r7).
// All weight loads happen post-gather: WsdpT is 40 KB, L2-resident.

__launch_bounds__(256, 6)
__global__ void din_att(const float* __restrict__ dense, const int* __restrict__ sparsei,
                        const int* __restrict__ seqi, const int* __restrict__ itemi,
                        const float* __restrict__ embS, const float* __restrict__ embQ,
                        const float* __restrict__ wqcT, const unsigned short* __restrict__ WsdpT,
                        const unsigned short* __restrict__ W2bT,
                        const float* __restrict__ ab1, const float* __restrict__ ab2,
                        const float* __restrict__ aWf, const float* __restrict__ abf,
                        unsigned short* __restrict__ Xg) {
  __shared__ __align__(16) char smem[21632];
  unsigned short* sX  = (unsigned short*)smem;             // 40 x 136
  unsigned short* sH1 = (unsigned short*)(smem + 10880);   // 40 x 104
  float* sQ     = (float*)(smem + 19200);                  // 128
  float* sQCp   = sQ + 128;                                // 160 (split-K qconst)
  float* sOther = sQCp + 160;                              // 200
  float* sAtt   = sOther + 200;                            // 40
  float* sLogit = sAtt + 40;                               // 40
  float* sMask  = sLogit + 40;                             // 40

  const int t = threadIdx.x;        // 0..255
  const int b = blockIdx.x;
  const int wv = t >> 6, ln = t & 63, m16 = ln & 15, quad = ln >> 4;

  // ---- phase 1: gathers + zero inits + mask cache ----
  if (t < 32) {
    int f = t >> 4, sub = t & 15;
    int idx = itemi[b * 2 + f];
    float4 v = *(const float4*)(embQ + ((size_t)(f * VV + idx)) * 64 + sub * 4);
    *(float4*)(sQ + f * 64 + sub * 4) = v;
  } else if (t < 80) {
    int j = t - 32, f = j >> 4, sub = j & 15;
    int idx = sparsei[b * 3 + f];
    float4 v = *(const float4*)(embS + ((size_t)(f * VV + idx)) * 64 + sub * 4);
    *(float4*)(sOther + 8 + f * 64 + sub * 4) = v;
  } else if (t < 88) {
    sOther[t - 80] = dense[b * 8 + (t - 80)];
  } else if (t < 128) {
    sLogit[t - 88] = 0.f;
  }
  for (int i = t; i < 1280; i += 256) {
    int r = i >> 4, sub = i & 15;
    int l = r >> 1, f = r & 1;
    int idx = seqi[b * 80 + r];
    float4 v = *(const float4*)(embQ + ((size_t)(f * VV + idx)) * 64 + sub * 4);
    ushort4 u;
    u.x = f2bf(v.x); u.y = f2bf(v.y); u.z = f2bf(v.z); u.w = f2bf(v.w);
    *(ushort4*)(sX + l * XS + f * 64 + sub * 4) = u;
    if (((r & 1) | sub) == 0) sMask[l] = (idx != 0) ? 0.f : NEG_INF_F;
  }
  for (int i = t; i < 320; i += 256) {   // sH1 K-pad cols 80..95, rows 0..39 (NaN guard)
    int r = i >> 3, c = i & 7;
    ((unsigned*)sH1)[r * 52 + 40 + c] = 0u;
  }
  __syncthreads();

  // ---- phase 2: split-K qconst (t<160) + own-nt B' build (load+fuse, minimal liveness) ----
  if (t < 160) {
    int h = (t < 80) ? t : t - 80;
    int k0 = (t < 80) ? 0 : 64;
    float acc = (t < 80) ? ab1[h] : 0.f;
    const float* wq = wqcT + h * 132 + k0;
    const float* qq = sQ + k0;
    for (int k = 0; k < 64; k += 4) {
      float4 w = *(const float4*)(wq + k);
      float4 q = *(const float4*)(qq + k);
      acc += q.x * w.x + q.y * w.y + q.z * w.z + q.w * w.w;
    }
    sQCp[t] = acc;
  }
  short8 Bp[4];
  {
    const unsigned short* br = WsdpT + (size_t)(wv * 16 + m16) * 256 + quad * 8;
#pragma unroll
    for (int kt = 0; kt < 4; kt++) {
      short8 w1 = *(const short8*)(br + kt * 32);
      short8 w2 = *(const short8*)(br + 128 + kt * 32);
      int k0 = quad * 8 + kt * 32;
      Bp[kt] = fuseB(w1, w2, *(const float4*)(sQ + k0), *(const float4*)(sQ + k0 + 4));
    }
  }
  __syncthreads();

  // ---- phase 3: layer1 MFMA, K=128, wave = N-tile; waves 0-2 inline nt=4 ----
  {
    const int h = wv * 16 + m16;
    const float qc = sQCp[h] + sQCp[80 + h];
#pragma unroll
    for (int mt = 0; mt < 3; mt++) {
      f32x4 acc = {0.f, 0.f, 0.f, 0.f};
      const unsigned short* ar = sX + (mt * 16 + m16) * XS + quad * 8;
#pragma unroll
      for (int kt = 0; kt < 4; kt++) {
        short8 a = *(const short8*)(ar + kt * 32);
        acc = __builtin_amdgcn_mfma_f32_16x16x32_bf16(a, Bp[kt], acc, 0, 0, 0);
      }
#pragma unroll
      for (int r = 0; r < 4; r++) {
        int l = mt * 16 + quad * 4 + r;
        if (l < 40) {
          float z = acc[r] + qc;
          sH1[l * HS + h] = f2bf(1.f / (1.f + __expf(-z)));
        }
      }
    }
    if (wv < 3) {   // nt = 4, mt = wv : load+fuse+mfma inline, no persistent frags
      const unsigned short* br = WsdpT + (size_t)(64 + m16) * 256 + quad * 8;
      const unsigned short* ar = sX + (wv * 16 + m16) * XS + quad * 8;
      f32x4 acc = {0.f, 0.f, 0.f, 0.f};
#pragma unroll
      for (int kt = 0; kt < 4; kt++) {
        short8 w1 = *(const short8*)(br + kt * 32);
        short8 w2 = *(const short8*)(br + 128 + kt * 32);
        int k0 = quad * 8 + kt * 32;
        short8 bp = fuseB(w1, w2, *(const float4*)(sQ + k0), *(const float4*)(sQ + k0 + 4));
        short8 a = *(const short8*)(ar + kt * 32);
        acc = __builtin_amdgcn_mfma_f32_16x16x32_bf16(a, bp, acc, 0, 0, 0);
      }
      int h4 = 64 + m16;
      float qc4 = sQCp[h4] + sQCp[80 + h4];
#pragma unroll
      for (int r = 0; r < 4; r++) {
        int l = wv * 16 + quad * 4 + r;
        if (l < 40) {
          float z = acc[r] + qc4;
          sH1[l * HS + h4] = f2bf(1.f / (1.f + __expf(-z)));
        }
      }
    }
  }
  __syncthreads();

  // ---- phase 4: layer2 MFMA + fused logit reduction into sLogit ----
  for (int tile = wv; tile < 9; tile += 4) {
    int mt = tile / 3, nt = tile % 3;
    f32x4 acc = {0.f, 0.f, 0.f, 0.f};
    const unsigned short* ar = sH1 + (mt * 16 + m16) * HS + quad * 8;
    const unsigned short* br = W2bT + (nt * 16 + m16) * 96 + quad * 8;
#pragma unroll
    for (int kt = 0; kt < 3; kt++) {
      short8 a = *(const short8*)(ar + kt * 32);
      short8 bb = *(const short8*)(br + kt * 32);
      acc = __builtin_amdgcn_mfma_f32_16x16x32_bf16(a, bb, acc, 0, 0, 0);
    }
    int j = nt * 16 + m16;
    float b2 = (j < 40) ? ab2[j] : 0.f;
    float wf = (j < 40) ? aWf[j] : 0.f;
    float c[4];
#pragma unroll
    for (int r = 0; r < 4; r++) {
      float h2 = 1.f / (1.f + __expf(-(acc[r] + b2)));
      c[r] = (j < 40) ? h2 * wf : 0.f;    // gate garbage j-lanes (NaN-safe select)
    }
#pragma unroll
    for (int off = 1; off < 16; off <<= 1) {
#pragma unroll
      for (int r = 0; r < 4; r++) c[r] += __shfl_xor(c[r], off, 64);
    }
    if (m16 == 0) {
#pragma unroll
      for (int r = 0; r < 4; r++) {
        int l = mt * 16 + quad * 4 + r;
        if (l < 40) atomicAdd(&sLogit[l], c[r]);
      }
    }
  }
  __syncthreads();

  // ---- phase 5: softmax (wave 0) || store item/other/pad cols of Xg (waves 1-3) ----
  if (wv == 0) {
    float logit = -3.0e38f;
    if (t < 40) logit = sLogit[t] + abf[0] + sMask[t];
    float mx = logit;
    for (int off = 32; off; off >>= 1) mx = fmaxf(mx, __shfl_xor(mx, off, 64));
    float ex = (t < 40) ? __expf(logit - mx) : 0.f;
    float sm = ex;
    for (int off = 32; off; off >>= 1) sm += __shfl_xor(sm, off, 64);
    if (t < 40) sAtt[t] = ex / sm;
  } else {
    int j = t - 64;                                  // 0..191
    unsigned* xr = (unsigned*)(Xg + (size_t)b * XGS);
    if (j < 64) {
      xr[64 + j] = (unsigned)f2bf(sQ[2 * j]) | ((unsigned)f2bf(sQ[2 * j + 1]) << 16);
    } else if (j < 164) {
      int p = j - 64;
      xr[128 + p] = (unsigned)f2bf(sOther[2 * p]) | ((unsigned)f2bf(sOther[2 * p + 1]) << 16);
    } else if (j < 176) {
      xr[228 + (j - 164)] = 0u;                      // K-pad cols 456..479
    }
  }
  __syncthreads();

  // ---- phase 6: attention pool -> Xg cols 0..127 ----
  if (t < 128) {
    float acc = 0.f;
    for (int l = 0; l < 40; l++) acc += sAtt[l] * bf2f(sX[l * XS + t]);
    Xg[(size_t)b * XGS + t] = f2bf(acc);
  }
}

// ---------------- kernel B: batched FFN GEMM, 16 rows per block ----------------

__launch_bounds__(256, 2)
__global__ void din_ffn(const unsigned short* __restrict__ Xg,
                        const unsigned short* __restrict__ W1fT, const float* __restrict__ b1p,
                        const float* __restrict__ fa1,
                        const unsigned short* __restrict__ W2fT, const float* __restrict__ fb2,
                        const float* __restrict__ fa2,
                        const float* __restrict__ oW, const float* __restrict__ ob,
                        float* __restrict__ out) {
  __shared__ __align__(16) unsigned short sXB[16 * 488];
  __shared__ __align__(16) unsigned short sH1B[16 * HS];
  __shared__ float sH2B[16 * 41];
  const int t = threadIdx.x, blk = blockIdx.x;
  const int wv = t >> 6, ln = t & 63, m16 = ln & 15, quad = ln >> 4;

  // prefetch GEMM1 B-fragments for nt = wv (15 frags, K=480)
  short8 Bf[15];
  {
    const unsigned short* br = W1fT + (size_t)(wv * 16 + m16) * 480 + quad * 8;
#pragma unroll
    for (int kt = 0; kt < 15; kt++) Bf[kt] = *(const short8*)(br + kt * 32);
  }

  // stage X tile (16 rows x 480 bf16) + zero H1 K-pad
  for (int i = t; i < 960; i += 256) {
    int r = i / 60, c = i % 60;
    *(uint4*)(sXB + r * 488 + c * 8) =
        *(const uint4*)(Xg + (size_t)(blk * 16 + r) * XGS + c * 8);
  }
  if (t < 128) {
    int r = t >> 3, c = t & 7;
    ((unsigned*)sH1B)[r * 52 + 40 + c] = 0u;
  }
  __syncthreads();

  // GEMM1: [16x480] @ [480x80]; wave = N-tile; wave 0 also does nt=4
  {
    int h = wv * 16 + m16;
    f32x4 acc = {0.f, 0.f, 0.f, 0.f};
    const unsigned short* ar = sXB + m16 * 488 + quad * 8;
#pragma unroll
    for (int kt = 0; kt < 15; kt++) {
      short8 a = *(const short8*)(ar + kt * 32);
      acc = __builtin_amdgcn_mfma_f32_16x16x32_bf16(a, Bf[kt], acc, 0, 0, 0);
    }
    float b1v = b1p[h], a1v = fa1[h];
#pragma unroll
    for (int r = 0; r < 4; r++) {
      int l = quad * 4 + r;
      float z = acc[r] + b1v;
      z = z > 0.f ? z : a1v * z;
      sH1B[l * HS + h] = f2bf(z);
    }
    if (wv == 0) {   // nt = 4
      short8 B4[15];
      const unsigned short* br = W1fT + (size_t)(64 + m16) * 480 + quad * 8;
#pragma unroll
      for (int kt = 0; kt < 15; kt++) B4[kt] = *(const short8*)(br + kt * 32);
      f32x4 acc4 = {0.f, 0.f, 0.f, 0.f};
#pragma unroll
      for (int kt = 0; kt < 15; kt++) {
        short8 a = *(const short8*)(ar + kt * 32);
        acc4 = __builtin_amdgcn_mfma_f32_16x16x32_bf16(a, B4[kt], acc4, 0, 0, 0);
      }
      int h4 = 64 + m16;
      float b1v4 = b1p[h4], a1v4 = fa1[h4];
#pragma unroll
      for (int r = 0; r < 4; r++) {
        int l = quad * 4 + r;
        float z = acc4[r] + b1v4;
        z = z > 0.f ? z : a1v4 * z;
        sH1B[l * HS + h4] = f2bf(z);
      }
    }
  }
  __syncthreads();

  // GEMM2: [16x96] @ [96x48], waves 0-2
  if (wv < 3) {
    f32x4 acc = {0.f, 0.f, 0.f, 0.f};
    const unsigned short* ar = sH1B + m16 * HS + quad * 8;
    const unsigned short* br = W2fT + (wv * 16 + m16) * 96 + quad * 8;
#pragma unroll
    for (int kt = 0; kt < 3; kt++) {
      short8 a = *(const short8*)(ar + kt * 32);
      short8 bb = *(const short8*)(br + kt * 32);
      acc = __builtin_amdgcn_mfma_f32_16x16x32_bf16(a, bb, acc, 0, 0, 0);
    }
    int j = wv * 16 + m16;
    if (j < 40) {
      float b2 = fb2[j], a2 = fa2[j];
#pragma unroll
      for (int r = 0; r < 4; r++) {
        int l = quad * 4 + r;
        float z = acc[r] + b2;
        sH2B[l * 41 + j] = z > 0.f ? z : a2 * z;
      }
    }
  }
  __syncthreads();

  // final dot(40) + sigmoid
  if (t < 16) {
    float acc = ob[0];
    for (int j = 0; j < 40; j++) acc += sH2B[t * 41 + j] * oW[j];
    out[blk * 16 + t] = 1.f / (1.f + __expf(-acc));
  }
}

// ---------------- launch ----------------

extern "C" void kernel_launch(void* const* d_in, const int* in_sizes, int n_in,
                              void* d_out, int out_size, void* d_ws, size_t ws_size,
                              hipStream_t stream) {
  const float* dense  = (const float*)d_in[0];
  const int*   sparsei = (const int*)d_in[1];
  const int*   seqi   = (const int*)d_in[2];
  const int*   itemi  = (const int*)d_in[3];
  const float* embS   = (const float*)d_in[4];
  const float* embQ   = (const float*)d_in[5];
  const float* aW1    = (const float*)d_in[6];
  const float* ab1    = (const float*)d_in[7];
  const float* aW2    = (const float*)d_in[8];
  const float* ab2    = (const float*)d_in[9];
  const float* aWf    = (const float*)d_in[10];
  const float* abf    = (const float*)d_in[11];
  const float* bng    = (const float*)d_in[12];
  const float* bnb    = (const float*)d_in[13];
  const float* bnm    = (const float*)d_in[14];
  const float* bnv    = (const float*)d_in[15];
  const float* fW1    = (const float*)d_in[16];
  const float* fb1    = (const float*)d_in[17];
  const float* fa1    = (const float*)d_in[18];
  const float* fW2    = (const float*)d_in[19];
  const float* fb2    = (const float*)d_in[20];
  const float* fa2    = (const float*)d_in[21];
  const float* oW     = (const float*)d_in[22];
  const float* ob     = (const float*)d_in[23];
  float* out = (float*)d_out;

  float* ws = (float*)d_ws;
  float* wqcT = ws;                                          // 10560 f
  float* b1p  = ws + 10560;                                  // 80 f
  unsigned short* WsdpT = (unsigned short*)(ws + 10640);     // 20480 u16 = 10240 f
  unsigned short* W2bT  = (unsigned short*)(ws + 20880);     // 4608 u16 = 2304 f
  unsigned short* W2fT  = (unsigned short*)(ws + 23184);     // 4608 u16 = 2304 f
  unsigned short* W1fT  = (unsigned short*)(ws + 25488);     // 38400 u16 = 19200 f
  unsigned short* Xg    = (unsigned short*)(ws + 44688);     // 8192*480 u16

  prep_all<<<306, 256, 0, stream>>>(aW1, wqcT, WsdpT, aW2, W2bT, fW2, W2fT,
                                    fW1, bng, bnv, W1fT, fb1, bnb, bnm, b1p);
  din_att<<<BB, 256, 0, stream>>>(dense, sparsei, seqi, itemi, embS, embQ,
                                  wqcT, WsdpT, W2bT, ab1, ab2, aWf, abf, Xg);
  din_ffn<<<512, 256, 0, stream>>>(Xg, W1fT, b1p, fa1, W2fT, fb2, fa2, oW, ob, out);
}